// Round 10
// baseline (433.868 us; speedup 1.0000x reference)
//
#include <hip/hip_runtime.h>

typedef __attribute__((ext_vector_type(8))) short bf16x8;
typedef __attribute__((ext_vector_type(4))) float f32x4;

static __device__ __forceinline__ unsigned short f2bf(float f) {
  unsigned u = __builtin_bit_cast(unsigned, f);
  unsigned r = u + 0x7fffu + ((u >> 16) & 1u);
  return (unsigned short)(r >> 16);
}
static __device__ __forceinline__ unsigned pkbf(float a, float b) {
  return (unsigned)f2bf(a) | ((unsigned)f2bf(b) << 16);
}

// Direct global->LDS staging (A-tiles only). Dest = wave-uniform base + lane*16.
#define GLOAD_LDS16(g, l)                                              \
  __builtin_amdgcn_global_load_lds(                                    \
      (const __attribute__((address_space(1))) void*)(g),              \
      (__attribute__((address_space(3))) void*)(l), 16, 0, 0)

// ---------------- k_qk: Q/K dwconv + Gram only (bx ELIMINATED) ---------------------
// ROUND-14. grid (64,8,4), block 256, bounds (256,3) — r9 proved the 64-reg clamp of
// bounds-4 spills this conv; r8 proved bounds-3 is clean (VGPR 84).
// vs r8/r9: v-conv, vpack/xpack, vx overlay, bx stores, 2 barriers all REMOVED
// (v now computed in k_gx with zero redundancy; x-half read directly there).
// Writes only gp (8.4 MB). One barrier total. Q/K numerics identical to r8/r9.
struct SmQ { float xs[4][324]; unsigned short qk[2][32][256]; };  // 5184B*4? no: 20736? -> 4*324*4=5184 + 32768 = 37,952 B

__global__ __launch_bounds__(256, 3) void k_qk(
    const float* __restrict__ x,
    const float* __restrict__ q_w, const float* __restrict__ q_b,
    const float* __restrict__ k_w, const float* __restrict__ k_b,
    float* __restrict__ gp)            // [4][8][64][32][32] partial Grams
{
  __shared__ SmQ sm;
  // XCD swizzle: each XCD owns 4 contiguous (b,h) slabs (FETCH 116->33 MB).
  const int lin = blockIdx.x + 64 * (blockIdx.y + 8 * blockIdx.z);
  const int nl = ((lin & 7) << 8) | (lin >> 3);
  const int t = nl & 63, h = (nl >> 6) & 7, b = nl >> 9;
  const int tid = threadIdx.x;
  __builtin_assume(tid < 256);
  const int wv = tid >> 6, lane = tid & 63;
  const int w4 = __builtin_amdgcn_readfirstlane(wv);  // wave-uniform -> scalar weight loads
  const int ty = t >> 3, tx = t & 7;
  const int y0 = ty * 16, x0 = tx * 16;
  const int py = lane >> 2, px0 = (lane & 3) * 4;

  // per-lane halo geometry: element r = lane + 64k; goff<0 => OOB/pad
  int goff[6];
  #pragma unroll
  for (int k = 0; k < 6; ++k) {
    int r = lane + 64 * k;
    int yy = r / 18, xx = r - yy * 18;
    int gy = y0 + yy - 1, gx = x0 + xx - 1;
    goff[k] = ((r < 324) && ((unsigned)gy < 128u) && ((unsigned)gx < 128u))
                  ? (gy * 128 + gx) : -1;
  }
  const float* cb = x + ((size_t)(b * 256 + h * 32 + w4 * 4)) * 16384;
  float hc[6], hn[6];
  #pragma unroll
  for (int k = 0; k < 6; ++k) { hc[k] = 0.f; if (goff[k] >= 0) hc[k] = cb[goff[k]]; }

  float* xw = &sm.xs[w4][0];   // wave-private strip
  #pragma unroll
  for (int pass = 0; pass < 2; ++pass) {
    const int cbase = h * 32 + pass * 16;
    #pragma unroll
    for (int j = 0; j < 4; ++j) {
      // stage current channel's halo (no barrier: one wave owns the strip)
      #pragma unroll
      for (int k = 0; k < 6; ++k) {
        int r = lane + 64 * k;
        if (r < 324) xw[r] = hc[k];
      }
      const bool last = (pass == 1) && (j == 3);
      const int nrel = (j < 3) ? (pass * 16 + j + 1) : 16;
      if (!last) {
        const float* np = cb + (size_t)nrel * 16384;
        #pragma unroll
        for (int k = 0; k < 6; ++k) { hn[k] = 0.f; if (goff[k] >= 0) hn[k] = np[goff[k]]; }
      }
      const int ch = cbase + w4 * 4 + j;          // wave-uniform
      float wq[9], wk[9];
      #pragma unroll
      for (int i2 = 0; i2 < 9; ++i2) {
        wq[i2] = q_w[ch * 9 + i2];
        wk[i2] = k_w[ch * 9 + i2];
      }
      const float bq = q_b[ch], bk = k_b[ch];
      float aq[4], ak[4];
      #pragma unroll
      for (int px = 0; px < 4; ++px) { aq[px] = bq; ak[px] = bk; }
      #pragma unroll
      for (int r = 0; r < 3; ++r) {
        const float* xrow = &xw[(py + r) * 18 + px0];
        float2 a01 = *(const float2*)&xrow[0];
        float2 a23 = *(const float2*)&xrow[2];
        float2 a45 = *(const float2*)&xrow[4];
        float rw[6];
        rw[0] = a01.x; rw[1] = a01.y; rw[2] = a23.x;
        rw[3] = a23.y; rw[4] = a45.x; rw[5] = a45.y;
        #pragma unroll
        for (int px = 0; px < 4; ++px)
          #pragma unroll
          for (int cx = 0; cx < 3; ++cx) {
            float xv = rw[px + cx];
            aq[px] += wq[r * 3 + cx] * xv;
            ak[px] += wk[r * 3 + cx] * xv;
          }
      }
      const int ah = pass * 16 + w4 * 4 + j;
      const int sw = (((lane >> 1) ^ (ah & 7)) << 3) + ((lane & 1) << 2);
      *(uint2*)&sm.qk[0][ah][sw] = make_uint2(pkbf(aq[0], aq[1]), pkbf(aq[2], aq[3]));
      *(uint2*)&sm.qk[1][ah][sw] = make_uint2(pkbf(ak[0], ak[1]), pkbf(ak[2], ak[3]));
      if (!last) {
        #pragma unroll
        for (int k = 0; k < 6; ++k) hc[k] = hn[k];
      }
    }
  }
  __syncthreads();   // all waves' qk rows complete

  // Gram quadrant per wave: K=256, swizzled frag reads
  const int qm = wv >> 1, qn = wv & 1;
  const int lrow = lane & 15, quad = lane >> 4;
  const int rowa = qm * 16 + lrow, rowb = qn * 16 + lrow;
  f32x4 acc = {0.f, 0.f, 0.f, 0.f};
  #pragma unroll
  for (int ks = 0; ks < 8; ++ks) {
    bf16x8 a  = *(const bf16x8*)&sm.qk[0][rowa][(((ks * 4 + quad) ^ (rowa & 7)) << 3)];
    bf16x8 bb = *(const bf16x8*)&sm.qk[1][rowb][(((ks * 4 + quad) ^ (rowb & 7)) << 3)];
    acc = __builtin_amdgcn_mfma_f32_16x16x32_bf16(a, bb, acc, 0, 0, 0);
  }
  float* gpb = gp + ((size_t)((b * 8 + h) * 64 + t)) * 1024;
  #pragma unroll
  for (int r = 0; r < 4; ++r)
    gpb[(qm * 16 + quad * 4 + r) * 32 + qn * 16 + lrow] = acc[r];
}

// ---------------- k_rs_prep: fused {reduce+softmax} + {kprep} ----------------------
__global__ __launch_bounds__(256) void k_rs_prep(
    const float* __restrict__ gp, const float* __restrict__ temp,
    float* __restrict__ attn,
    const float* __restrict__ out_w, const float* __restrict__ out_b,
    const float* __restrict__ fusion_w, const float* __restrict__ fusion_b,
    const float* __restrict__ gamma,
    float* __restrict__ W1g, float* __restrict__ bias_tot,
    unsigned short* __restrict__ Wcat) {
  const int bi = blockIdx.x;
  const int tid = threadIdx.x;

  if (bi >= 128) {  // ---- kprep path ----
    const int o = bi - 128;
    const int c = tid;
    const float g = gamma[0];
    float acc = 0.f, bacc = 0.f;
    #pragma unroll 8
    for (int t = 0; t < 256; ++t) {
      float fw = fusion_w[o*512 + t];
      acc  += fw * out_w[t*256 + c];
      bacc += fw * out_b[t];
    }
    W1g[o*256 + c] = g * acc;
    if (c == 0) bias_tot[o] = g * bacc + fusion_b[o];
    unsigned short w2b = f2bf(fusion_w[o*512 + 256 + c]);
    const int col = ((c >> 5) << 6) + 32 + (c & 31);   // x-half slot
    for (int b = 0; b < 4; ++b)
      Wcat[((size_t)(b*256 + o))*512 + col] = w2b;
    return;
  }

  // ---- reduce + softmax path ----
  const int cs = bi & 3, h = (bi >> 2) & 7, b = bi >> 5;
  const int lc = tid >> 5, d = tid & 31;
  const int c = cs * 8 + lc;
  const float* base = gp + ((size_t)((b*8 + h)*64))*1024 + c*32 + d;
  float s = 0.f;
  #pragma unroll
  for (int g = 0; g < 8; ++g) {
    float p = 0.f;
    #pragma unroll
    for (int i = 0; i < 8; ++i) p += base[(size_t)(g*8 + i)*1024];
    s += p;
  }
  s *= temp[h];
  float m = s;
  #pragma unroll
  for (int off = 16; off; off >>= 1) m = fmaxf(m, __shfl_xor(m, off));
  float e = __expf(s - m);
  float sum = e;
  #pragma unroll
  for (int off = 16; off; off >>= 1) sum += __shfl_xor(sum, off);
  attn[((size_t)((b*8 + h)*32 + c))*32 + d] = e / sum;
}

// ---------------- k_compose: M_b = W1g @ attn_blockdiag -> Wcat v-cols -------------
__global__ __launch_bounds__(256) void k_compose(
    const float* __restrict__ W1g, const float* __restrict__ attn,
    unsigned short* __restrict__ Wcat) {
  const int o = blockIdx.x, b = blockIdx.y;
  const int e = threadIdx.x;            // e = global v-channel h*32+d
  const int h = e >> 5, d = e & 31;
  const float* ab = attn + ((size_t)((b*8 + h)*32))*32 + d;
  const float* wb = W1g + o*256 + h*32;
  float s = 0.f;
  #pragma unroll
  for (int c2 = 0; c2 < 32; ++c2) s += wb[c2] * ab[c2*32];
  Wcat[((size_t)(b*256 + o))*512 + ((e >> 5) << 6) + (e & 31)] = f2bf(s);
}

// ---- B-tile staging for k_gx: on-the-fly v-dwconv (even steps) / x-cast (odd) -----
// Thread map: wq = tid>>6 (wave-uniform channel-group -> scalar weight loads),
// n = tid&63 (pixel). Pixels nbase..nbase+63 are one half-row: y uniform.
// +-1 columns via intra-wave shfl; 2 edge lanes load directly.
// v FMA order = bias-first, dy-outer, (left,mid,right) inner == old k_qkv v path
// -> bit-identical values. Bl col-swizzle key=(n^(n>>2))&3 -> 8 start-banks x 8
// lanes on both the wave-uniform store and the frag read (b128-ideal).
static __device__ __forceinline__ void stage_B(
    const float* __restrict__ x, const float* __restrict__ v_w,
    const float* __restrict__ v_b, int b, int nbase, int tid, int s,
    unsigned short (*__restrict__ Blb)[32]) {
  const int wq = tid >> 6, n = tid & 63;
  const int ng = nbase + n;
  const int chb = (s >> 1) * 32 + wq * 8;
  unsigned pk0, pk1, pk2, pk3;
  if (s & 1) {  // x-step: direct f32 -> bf16
    const float* xp = x + ((size_t)(b * 256 + chb)) * 16384 + ng;
    pk0 = pkbf(xp[0],           xp[16384]);
    pk1 = pkbf(xp[2 * 16384],   xp[3 * 16384]);
    pk2 = pkbf(xp[4 * 16384],   xp[5 * 16384]);
    pk3 = pkbf(xp[6 * 16384],   xp[7 * 16384]);
  } else {      // v-step: 3x3 dwconv at pixel ng for 8 channels
    const int y = ng >> 7, xc = ng & 127;
    float av8[8];
    #pragma unroll
    for (int u = 0; u < 8; ++u) {
      const int ch = chb + u;
      const float* wp = v_w + ch * 9;        // wave-uniform -> scalar
      const float* rp = x + ((size_t)(b * 256 + ch)) * 16384 + xc;
      float av = v_b[ch];
      #pragma unroll
      for (int dy = 0; dy < 3; ++dy) {
        const int gy = y + dy - 1;           // uniform across wave
        if ((unsigned)gy < 128u) {
          const float* row = rp + gy * 128;  // &x[ch][gy][xc]
          float xm = row[0];
          float xl = __shfl_up(xm, 1);
          float xr = __shfl_down(xm, 1);
          if (n == 0)  xl = (xc > 0)   ? row[-1] : 0.f;
          if (n == 63) xr = (xc < 127) ? row[1]  : 0.f;
          av += wp[dy * 3 + 0] * xl;
          av += wp[dy * 3 + 1] * xm;
          av += wp[dy * 3 + 2] * xr;
        }
      }
      av8[u] = av;
    }
    pk0 = pkbf(av8[0], av8[1]); pk1 = pkbf(av8[2], av8[3]);
    pk2 = pkbf(av8[4], av8[5]); pk3 = pkbf(av8[6], av8[7]);
  }
  const int key = (n ^ (n >> 2)) & 3;
  *(uint4*)&Blb[n][((wq ^ key) << 3)] = make_uint4(pk0, pk1, pk2, pk3);
}

// ---------------- k_gx: out = Wcat @ [v;x] + bias, B computed ON THE FLY -----------
// ROUND-14. bx (67 MB round-trip) eliminated: step ks covers cols ks*32..+31 which
// are purely-v (ks even) or purely-x (ks odd) of head h=ks>>1 — each staged from x
// directly. Each (b,c,n) v-value computed exactly once across the grid (no
// redundancy). A-path (Wcat via gload_lds) and MFMA order unchanged -> out is
// bit-identical to the bx version. LDS 40,960 B (3 blocks/CU).
__global__ __launch_bounds__(256) void k_gx(
    const unsigned short* __restrict__ Wcat,
    const float* __restrict__ x,
    const float* __restrict__ v_w, const float* __restrict__ v_b,
    const float* __restrict__ bias_tot,
    float* __restrict__ out) {
  __shared__ unsigned short Al[2][256][32];  // 2 x 16,384 B
  __shared__ unsigned short Bl[2][64][32];   // 2 x  4,096 B
  const int nt = blockIdx.x, b = blockIdx.y;
  const int tid = threadIdx.x;
  const int wv = tid >> 6, lane = tid & 63;
  const int lrow = lane & 15, quad = lane >> 4;
  const int nbase = nt * 64;
  const unsigned short* Ab = Wcat + (size_t)b * 256 * 512;
  f32x4 acc[4][4] = {};

  const int srow = tid >> 2;
  const int sq4 = tid & 3;
  const unsigned short* apr = Ab + (size_t)srow * 512 + sq4 * 8;

  // stage chunk 0 -> buf 0
  #pragma unroll
  for (int g = 0; g < 4; ++g)
    GLOAD_LDS16(apr + (size_t)g * 64 * 512, &Al[0][wv * 16 + g * 64][0]);
  stage_B(x, v_w, v_b, b, nbase, tid, 0, Bl[0]);
  __syncthreads();

  for (int ks = 0; ks < 16; ++ks) {
    const int cur = ks & 1;
    if (ks < 15) {
      const int k0 = (ks + 1) * 32;
      const int nxt = cur ^ 1;
      #pragma unroll
      for (int g = 0; g < 4; ++g)
        GLOAD_LDS16(apr + (size_t)g * 64 * 512 + k0, &Al[nxt][wv * 16 + g * 64][0]);
      stage_B(x, v_w, v_b, b, nbase, tid, ks + 1, Bl[nxt]);
    }
    bf16x8 af[4], bfv[4];
    #pragma unroll
    for (int i = 0; i < 4; ++i)
      af[i] = *(const bf16x8*)&Al[cur][wv * 64 + i * 16 + lrow][quad * 8];
    #pragma unroll
    for (int j = 0; j < 4; ++j) {
      const int row = j * 16 + lrow;
      const int key = (row ^ (row >> 2)) & 3;
      bfv[j] = *(const bf16x8*)&Bl[cur][row][((quad ^ key) << 3)];
    }
    #pragma unroll
    for (int i = 0; i < 4; ++i)
      #pragma unroll
      for (int j = 0; j < 4; ++j)
        acc[i][j] = __builtin_amdgcn_mfma_f32_16x16x32_bf16(af[i], bfv[j], acc[i][j], 0, 0, 0);
    __syncthreads();  // drains in-flight A-gloads + releases cur for restage
  }

  #pragma unroll
  for (int i = 0; i < 4; ++i) {
    #pragma unroll
    for (int r = 0; r < 4; ++r) {
      const int o = wv*64 + i*16 + quad*4 + r;
      const float bias = bias_tot[o];
      #pragma unroll
      for (int j = 0; j < 4; ++j) {
        const int n = nbase + j*16 + lrow;
        out[((size_t)(b*256 + o))*16384 + n] = acc[i][j][r] + bias;
      }
    }
  }
}

extern "C" void kernel_launch(void* const* d_in, const int* in_sizes, int n_in,
                              void* d_out, int out_size, void* d_ws, size_t ws_size,
                              hipStream_t stream) {
  const float* x        = (const float*)d_in[0];
  const float* q_w      = (const float*)d_in[1];
  const float* q_b      = (const float*)d_in[2];
  const float* k_w      = (const float*)d_in[3];
  const float* k_b      = (const float*)d_in[4];
  const float* v_w      = (const float*)d_in[5];
  const float* v_b      = (const float*)d_in[6];
  const float* out_w    = (const float*)d_in[7];
  const float* out_b    = (const float*)d_in[8];
  const float* fusion_w = (const float*)d_in[9];
  const float* fusion_b = (const float*)d_in[10];
  const float* temp     = (const float*)d_in[11];
  const float* gamma    = (const float*)d_in[12];
  float* out = (float*)d_out;

  char* ws = (char*)d_ws;
  float* gp            = (float*)(ws);                     //  8,388,608 B
  float* attn          = (float*)(ws + 8388608);           //    131,072 B
  float* W1g           = (float*)(ws + 8519680);           //    262,144 B
  float* bias_tot      = (float*)(ws + 8781824);           //      1,024 B
  unsigned short* Wcat = (unsigned short*)(ws + 8782848);  //  1,048,576 B (total ~9.8 MB)

  k_qk<<<dim3(64, 8, 4), dim3(256), 0, stream>>>(x, q_w, q_b, k_w, k_b, gp);
  k_rs_prep<<<dim3(384), dim3(256), 0, stream>>>(gp, temp, attn,
                                                 out_w, out_b, fusion_w, fusion_b,
                                                 gamma, W1g, bias_tot, Wcat);
  k_compose<<<dim3(256, 4), dim3(256), 0, stream>>>(W1g, attn, Wcat);
  k_gx<<<dim3(256, 4), dim3(256), 0, stream>>>(Wcat, x, v_w, v_b, bias_tot, out);
}

// Round 11
// 217.125 us; speedup vs baseline: 1.9982x; 1.9982x over previous
//
#include <hip/hip_runtime.h>

typedef __attribute__((ext_vector_type(8))) short bf16x8;
typedef __attribute__((ext_vector_type(4))) float f32x4;

static __device__ __forceinline__ unsigned short f2bf(float f) {
  unsigned u = __builtin_bit_cast(unsigned, f);
  unsigned r = u + 0x7fffu + ((u >> 16) & 1u);
  return (unsigned short)(r >> 16);
}
static __device__ __forceinline__ unsigned pkbf(float a, float b) {
  return (unsigned)f2bf(a) | ((unsigned)f2bf(b) << 16);
}

// Direct global->LDS staging (no VGPR round-trip). Dest must be wave-uniform
// base + lane*16 (linear), so LDS tiles below are unpadded.
#define GLOAD_LDS16(g, l)                                              \
  __builtin_amdgcn_global_load_lds(                                    \
      (const __attribute__((address_space(1))) void*)(g),              \
      (__attribute__((address_space(3))) void*)(l), 16, 0, 0)

// ---------------- k_qkv: wave-private halo staging (pipelined), dwconv, Grams ------
// ROUND-15 = exact restore of ROUND-12 (benched 220.9 us, best). grid (64,8,4),
// block 256, LDS 37,952 B, bounds (256,3) — the only spill-free occupancy point
// (bounds-4's 64-reg clamp spills this conv: proven r10/r11/r13).
// Per-wave private 324-float strip, hc/hn per-channel halo pipeline, zero barriers
// in the conv phase; v computed here (halos LDS-resident) and shipped via bx —
// r14 proved recomputing v in the GEMM is 3x read-amplified + latency-serial.
struct SmA { float xs[4][324]; unsigned short qk[2][32][256]; };  // 5184 + 32768
union SmU { SmA a; unsigned short vx[256][72]; };                 // vx 36864; union 37952

__global__ __launch_bounds__(256, 3) void k_qkv(
    const float* __restrict__ x,
    const float* __restrict__ q_w, const float* __restrict__ q_b,
    const float* __restrict__ k_w, const float* __restrict__ k_b,
    const float* __restrict__ v_w, const float* __restrict__ v_b,
    unsigned short* __restrict__ bx,   // [4][16384][512] bf16, col = h*64 + {v:0-31, x:32-63}
    float* __restrict__ gp)            // [4][8][64][32][32] partial Grams
{
  __shared__ SmU sm;
  // XCD swizzle: 2048 wgs round-robin across 8 XCDs -> each XCD owns 4 contiguous
  // (b,h) slabs (FETCH 116->33 MB).
  const int lin = blockIdx.x + 64 * (blockIdx.y + 8 * blockIdx.z);
  const int nl = ((lin & 7) << 8) | (lin >> 3);
  const int t = nl & 63, h = (nl >> 6) & 7, b = nl >> 9;
  const int tid = threadIdx.x;
  __builtin_assume(tid < 256);
  const int wv = tid >> 6, lane = tid & 63;
  const int w4 = __builtin_amdgcn_readfirstlane(wv);  // wave-uniform -> scalar weight loads
  const int ty = t >> 3, tx = t & 7;
  const int y0 = ty * 16, x0 = tx * 16;
  const int py = lane >> 2, px0 = (lane & 3) * 4;

  // ---- per-lane halo geometry: element r = lane + 64k of the 324-elem strip ------
  int goff[6]; bool gok[6];
  #pragma unroll
  for (int k = 0; k < 6; ++k) {
    int r = lane + 64 * k;
    int yy = r / 18, xx = r - yy * 18;
    int gy = y0 + yy - 1, gx = x0 + xx - 1;
    gok[k] = (r < 324) && ((unsigned)gy < 128u) && ((unsigned)gx < 128u);
    goff[k] = gy * 128 + gx;
  }
  const float* cb = x + ((size_t)(b * 256 + h * 32 + w4 * 4)) * 16384;
  // channel visit order: pass 0 -> rel offs {0,1,2,3}, pass 1 -> {16,17,18,19}
  float hc[6], hn[6];
  #pragma unroll
  for (int k = 0; k < 6; ++k) hc[k] = gok[k] ? cb[goff[k]] : 0.f;  // channel rel 0

  float* xw = &sm.a.xs[w4][0];   // wave-private strip
  uint2 vpack[2][4], xpack[2][4];
  #pragma unroll
  for (int pass = 0; pass < 2; ++pass) {
    const int cbase = h * 32 + pass * 16;
    float vvf[4][4], xxf[4][4];
    #pragma unroll
    for (int j = 0; j < 4; ++j) {
      // stage current channel's halo into the wave-private strip (no barrier:
      // one wave owns the strip; same-wave DS ops are FIFO-ordered)
      #pragma unroll
      for (int k = 0; k < 6; ++k) {
        int r = lane + 64 * k;
        if (r < 324) xw[r] = hc[k];
      }
      // issue NEXT channel's halo loads (in flight under this channel's conv)
      const bool last = (pass == 1) && (j == 3);
      const int nrel = (j < 3) ? (pass * 16 + j + 1) : 16;  // {1,2,3,16} / {17,18,19,-}
      if (!last) {
        const float* np = cb + (size_t)nrel * 16384;
        #pragma unroll
        for (int k = 0; k < 6; ++k) hn[k] = gok[k] ? np[goff[k]] : 0.f;
      }
      const int ch = cbase + w4 * 4 + j;          // wave-uniform
      float wq[9], wk[9], wvv[9];
      #pragma unroll
      for (int i2 = 0; i2 < 9; ++i2) {
        wq[i2]  = q_w[ch * 9 + i2];
        wk[i2]  = k_w[ch * 9 + i2];
        wvv[i2] = v_w[ch * 9 + i2];
      }
      const float bq = q_b[ch], bk = k_b[ch], bv = v_b[ch];
      float win[3][6];
      #pragma unroll
      for (int r = 0; r < 3; ++r) {
        const float* xrow = &xw[(py + r) * 18 + px0];
        float2 a01 = *(const float2*)&xrow[0];
        float2 a23 = *(const float2*)&xrow[2];
        float2 a45 = *(const float2*)&xrow[4];
        win[r][0] = a01.x; win[r][1] = a01.y;
        win[r][2] = a23.x; win[r][3] = a23.y;
        win[r][4] = a45.x; win[r][5] = a45.y;
      }
      const int ah = pass * 16 + w4 * 4 + j;
      float q4[4], k4[4];
      #pragma unroll
      for (int px = 0; px < 4; ++px) {
        float aq = bq, ak = bk, av = bv;
        #pragma unroll
        for (int r = 0; r < 3; ++r)
          #pragma unroll
          for (int cx = 0; cx < 3; ++cx) {
            float xv = win[r][px + cx];
            aq += wq[r * 3 + cx] * xv;
            ak += wk[r * 3 + cx] * xv;
            av += wvv[r * 3 + cx] * xv;
          }
        q4[px] = aq; k4[px] = ak;
        vvf[j][px] = av;
        xxf[j][px] = win[1][px + 1];
      }
      const int sw = (((lane >> 1) ^ (ah & 7)) << 3) + ((lane & 1) << 2);
      *(uint2*)&sm.a.qk[0][ah][sw] = make_uint2(pkbf(q4[0], q4[1]), pkbf(q4[2], q4[3]));
      *(uint2*)&sm.a.qk[1][ah][sw] = make_uint2(pkbf(k4[0], k4[1]), pkbf(k4[2], k4[3]));
      if (!last) {
        #pragma unroll
        for (int k = 0; k < 6; ++k) hc[k] = hn[k];
      }
    }
    #pragma unroll
    for (int px = 0; px < 4; ++px) {
      vpack[pass][px] = make_uint2(pkbf(vvf[0][px], vvf[1][px]), pkbf(vvf[2][px], vvf[3][px]));
      xpack[pass][px] = make_uint2(pkbf(xxf[0][px], xxf[1][px]), pkbf(xxf[2][px], xxf[3][px]));
    }
  }
  __syncthreads();   // all waves' qk rows complete

  // Gram quadrant per wave: K=256, swizzled frag reads
  const int qm = wv >> 1, qn = wv & 1;
  const int lrow = lane & 15, quad = lane >> 4;
  const int rowa = qm * 16 + lrow, rowb = qn * 16 + lrow;
  f32x4 acc = {0.f, 0.f, 0.f, 0.f};
  #pragma unroll
  for (int ks = 0; ks < 8; ++ks) {
    bf16x8 a  = *(const bf16x8*)&sm.a.qk[0][rowa][(((ks * 4 + quad) ^ (rowa & 7)) << 3)];
    bf16x8 bb = *(const bf16x8*)&sm.a.qk[1][rowb][(((ks * 4 + quad) ^ (rowb & 7)) << 3)];
    acc = __builtin_amdgcn_mfma_f32_16x16x32_bf16(a, bb, acc, 0, 0, 0);
  }
  float* gpb = gp + ((size_t)((b * 8 + h) * 64 + t)) * 1024;
  #pragma unroll
  for (int r = 0; r < 4; ++r)
    gpb[(qm * 16 + quad * 4 + r) * 32 + qn * 16 + lrow] = acc[r];

  __syncthreads();  // qk dead -> vx overlay

  const int chi = wv >> 1, half = wv & 1;
  #pragma unroll
  for (int pass = 0; pass < 2; ++pass)
    #pragma unroll
    for (int px = 0; px < 4; ++px) {
      int n = py * 16 + px0 + px;
      int key = (n >> 3) & 7;
      int cv = pass * 2 + chi;
      int cx2 = 4 + pass * 2 + chi;
      *(uint2*)&sm.vx[n][((cv ^ key) << 3) + (half << 2)] = vpack[pass][px];
      *(uint2*)&sm.vx[n][((cx2 ^ key) << 3) + (half << 2)] = xpack[pass][px];
    }
  __syncthreads();

  #pragma unroll
  for (int it = 0; it < 8; ++it) {
    int n = it * 32 + (tid >> 3);
    int m = tid & 7;
    int key = (n >> 3) & 7;
    uint4 val = *(const uint4*)&sm.vx[n][((m ^ key) << 3)];
    int pyn = n >> 4, pxn = n & 15;
    int ng = (y0 + pyn) * 128 + x0 + pxn;
    *(uint4*)&bx[((size_t)b * 16384 + ng) * 512 + h * 64 + m * 8] = val;
  }
}

// ---------------- k_rs_prep: fused {reduce+softmax} + {kprep} ----------------------
// blocks [0,128): softmax (4-way c-split, shfl_xor row reductions)
// blocks [128,384): kprep — W1g/bias_tot/Wcat-x
__global__ __launch_bounds__(256) void k_rs_prep(
    const float* __restrict__ gp, const float* __restrict__ temp,
    float* __restrict__ attn,
    const float* __restrict__ out_w, const float* __restrict__ out_b,
    const float* __restrict__ fusion_w, const float* __restrict__ fusion_b,
    const float* __restrict__ gamma,
    float* __restrict__ W1g, float* __restrict__ bias_tot,
    unsigned short* __restrict__ Wcat) {
  const int bi = blockIdx.x;
  const int tid = threadIdx.x;

  if (bi >= 128) {  // ---- kprep path ----
    const int o = bi - 128;
    const int c = tid;
    const float g = gamma[0];
    float acc = 0.f, bacc = 0.f;
    #pragma unroll 8
    for (int t = 0; t < 256; ++t) {
      float fw = fusion_w[o*512 + t];
      acc  += fw * out_w[t*256 + c];
      bacc += fw * out_b[t];
    }
    W1g[o*256 + c] = g * acc;
    if (c == 0) bias_tot[o] = g * bacc + fusion_b[o];
    unsigned short w2b = f2bf(fusion_w[o*512 + 256 + c]);
    const int col = ((c >> 5) << 6) + 32 + (c & 31);   // x-half slot
    for (int b = 0; b < 4; ++b)
      Wcat[((size_t)(b*256 + o))*512 + col] = w2b;
    return;
  }

  // ---- reduce + softmax path ----
  const int cs = bi & 3, h = (bi >> 2) & 7, b = bi >> 5;
  const int lc = tid >> 5, d = tid & 31;
  const int c = cs * 8 + lc;
  const float* base = gp + ((size_t)((b*8 + h)*64))*1024 + c*32 + d;
  float s = 0.f;
  #pragma unroll
  for (int g = 0; g < 8; ++g) {
    float p = 0.f;
    #pragma unroll
    for (int i = 0; i < 8; ++i) p += base[(size_t)(g*8 + i)*1024];
    s += p;
  }
  s *= temp[h];
  float m = s;
  #pragma unroll
  for (int off = 16; off; off >>= 1) m = fmaxf(m, __shfl_xor(m, off));
  float e = __expf(s - m);
  float sum = e;
  #pragma unroll
  for (int off = 16; off; off >>= 1) sum += __shfl_xor(sum, off);
  attn[((size_t)((b*8 + h)*32 + c))*32 + d] = e / sum;
}

// ---------------- k_compose: M_b = W1g @ attn_blockdiag -> Wcat v-cols -------------
__global__ __launch_bounds__(256) void k_compose(
    const float* __restrict__ W1g, const float* __restrict__ attn,
    unsigned short* __restrict__ Wcat) {
  const int o = blockIdx.x, b = blockIdx.y;
  const int e = threadIdx.x;            // e = global v-channel h*32+d
  const int h = e >> 5, d = e & 31;
  const float* ab = attn + ((size_t)((b*8 + h)*32))*32 + d;
  const float* wb = W1g + o*256 + h*32;
  float s = 0.f;
  #pragma unroll
  for (int c2 = 0; c2 < 32; ++c2) s += wb[c2] * ab[c2*32];
  Wcat[((size_t)(b*256 + o))*512 + ((e >> 5) << 6) + (e & 31)] = f2bf(s);
}

// ---------------- k_gemm: out = Wcat[256x512] @ [v;x][512x16384] + bias ------------
// global_load_lds staging, unpadded linear LDS tiles (conflict-free for b128 frag
// reads at 64-B row stride). LDS 40,960 B. Sits at its ~134 MB memory floor
// (r4 A/B: staging rewrite time-neutral; r14: on-the-fly B recompute 3x worse).
__global__ __launch_bounds__(256) void k_gemm(
    const unsigned short* __restrict__ Wcat,
    const unsigned short* __restrict__ bx,
    const float* __restrict__ bias_tot,
    float* __restrict__ out) {
  __shared__ unsigned short Al[2][256][32];  // 2 x 16,384 B
  __shared__ unsigned short Bl[2][64][32];   // 2 x  4,096 B
  const int nt = blockIdx.x, b = blockIdx.y;
  const int tid = threadIdx.x;
  const int wv = tid >> 6, lane = tid & 63;
  const int lrow = lane & 15, quad = lane >> 4;
  const int nbase = nt * 64;
  const unsigned short* Ab = Wcat + (size_t)b * 256 * 512;
  const unsigned short* Bb = bx + ((size_t)b * 16384 + nbase) * 512;
  f32x4 acc[4][4] = {};

  const int srow = tid >> 2;
  const int sq4 = tid & 3;
  const unsigned short* apr = Ab + (size_t)srow * 512 + sq4 * 8;
  const unsigned short* bpr = Bb + (size_t)srow * 512 + sq4 * 8;

  // stage chunk 0 -> buf 0
  #pragma unroll
  for (int g = 0; g < 4; ++g)
    GLOAD_LDS16(apr + (size_t)g * 64 * 512, &Al[0][wv * 16 + g * 64][0]);
  GLOAD_LDS16(bpr, &Bl[0][wv * 16][0]);
  __syncthreads();

  for (int ks = 0; ks < 16; ++ks) {
    const int cur = ks & 1;
    if (ks < 15) {
      const int k0 = (ks + 1) * 32;
      const int nxt = cur ^ 1;
      #pragma unroll
      for (int g = 0; g < 4; ++g)
        GLOAD_LDS16(apr + (size_t)g * 64 * 512 + k0, &Al[nxt][wv * 16 + g * 64][0]);
      GLOAD_LDS16(bpr + k0, &Bl[nxt][wv * 16][0]);
    }
    bf16x8 af[4], bfv[4];
    #pragma unroll
    for (int i = 0; i < 4; ++i)
      af[i] = *(const bf16x8*)&Al[cur][wv * 64 + i * 16 + lrow][quad * 8];
    #pragma unroll
    for (int j = 0; j < 4; ++j)
      bfv[j] = *(const bf16x8*)&Bl[cur][j * 16 + lrow][quad * 8];
    #pragma unroll
    for (int i = 0; i < 4; ++i)
      #pragma unroll
      for (int j = 0; j < 4; ++j)
        acc[i][j] = __builtin_amdgcn_mfma_f32_16x16x32_bf16(af[i], bfv[j], acc[i][j], 0, 0, 0);
    __syncthreads();  // drains in-flight gloads (next buf ready) + read-release of cur
  }

  #pragma unroll
  for (int i = 0; i < 4; ++i) {
    #pragma unroll
    for (int r = 0; r < 4; ++r) {
      const int o = wv*64 + i*16 + quad*4 + r;
      const float bias = bias_tot[o];
      #pragma unroll
      for (int j = 0; j < 4; ++j) {
        const int n = nbase + j*16 + lrow;
        out[((size_t)(b*256 + o))*16384 + n] = acc[i][j][r] + bias;
      }
    }
  }
}

extern "C" void kernel_launch(void* const* d_in, const int* in_sizes, int n_in,
                              void* d_out, int out_size, void* d_ws, size_t ws_size,
                              hipStream_t stream) {
  const float* x        = (const float*)d_in[0];
  const float* q_w      = (const float*)d_in[1];
  const float* q_b      = (const float*)d_in[2];
  const float* k_w      = (const float*)d_in[3];
  const float* k_b      = (const float*)d_in[4];
  const float* v_w      = (const float*)d_in[5];
  const float* v_b      = (const float*)d_in[6];
  const float* out_w    = (const float*)d_in[7];
  const float* out_b    = (const float*)d_in[8];
  const float* fusion_w = (const float*)d_in[9];
  const float* fusion_b = (const float*)d_in[10];
  const float* temp     = (const float*)d_in[11];
  const float* gamma    = (const float*)d_in[12];
  float* out = (float*)d_out;

  char* ws = (char*)d_ws;
  unsigned short* bx   = (unsigned short*)(ws);             // 67,108,864 B
  float* gp            = (float*)(ws + 67108864);           //  8,388,608 B
  float* attn          = (float*)(ws + 75497472);           //    131,072 B
  float* W1g           = (float*)(ws + 75628544);           //    262,144 B
  float* bias_tot      = (float*)(ws + 75890688);           //      1,024 B
  unsigned short* Wcat = (unsigned short*)(ws + 75891712);  //  1,048,576 B (total ~77 MB)

  k_qkv<<<dim3(64, 8, 4), dim3(256), 0, stream>>>(x, q_w, q_b, k_w, k_b, v_w, v_b, bx, gp);
  k_rs_prep<<<dim3(384), dim3(256), 0, stream>>>(gp, temp, attn,
                                                 out_w, out_b, fusion_w, fusion_b,
                                                 gamma, W1g, bias_tot, Wcat);
  k_compose<<<dim3(256, 4), dim3(256), 0, stream>>>(W1g, attn, Wcat);
  k_gemm<<<dim3(256, 4), dim3(256), 0, stream>>>(Wcat, bx, bias_tot, out);
}